// Round 6
// baseline (255.882 us; speedup 1.0000x reference)
//
#include <hip/hip_runtime.h>
#include <math.h>

// Problem constants (fixed by setup_inputs)
#define T_TOKENS 32768
#define NEXP     16
#define HID      4096
#define MT       8            // tokens per wave
#define WAVES    8            // waves per block -> 64 tokens/block
#define D4       (HID / 4)    // 1024 f32x4 per row
#define HALF     (D4 / 2)     // 512 f32x4 per half-row
#define NC       (HALF / 64)  // 8 chunk-iterations per phase

typedef float f32x4 __attribute__((ext_vector_type(4)));

// Two-phase mega-stage (128 KiB LDS = all 16 experts x half hidden) + 3 sync
// points per block (R5), now with DEPTH-2 h prefetch: 3 rotating register
// buffers keep 16 h-loads (16 KiB) in flight per wave at all times, doubling
// per-CU outstanding reads (64 -> 128 KiB) to lift the queue-equilibrium BW.
__global__ __launch_bounds__(512, 2) void moe_gate_kernel(
    const float* __restrict__ h,   // [T, HID]
    const float* __restrict__ w,   // [NEXP, HID]
    float* __restrict__ out)       // [2*T] indices (as float), then [2*T] weights
{
    __shared__ f32x4 sw[NEXP][HALF];               // 128 KiB, single-buffered

    const int lane = threadIdx.x & 63;
    const int wv   = threadIdx.x >> 6;             // wave id (0..7)
    const int t0   = blockIdx.x * (MT * WAVES) + wv * MT;
    // t0 is wave-uniform by construction; force SGPR so the 8 row bases are
    // scalar (saves ~16 VGPRs -> depth-2 prefetch fits under 256).
    const int t0u  = __builtin_amdgcn_readfirstlane(t0);
    const f32x4* __restrict__ hb =
        reinterpret_cast<const f32x4*>(h + (size_t)t0u * HID);
    const f32x4* __restrict__ w4 = reinterpret_cast<const f32x4*>(w);

    float acc[MT * NEXP];
    #pragma unroll
    for (int i = 0; i < MT * NEXP; ++i) acc[i] = 0.0f;

    // Wave wv stages experts 2wv,2wv+1 (8 chunks each = 16 loads of 1 KiB).
#define STAGE(kh_) do {                                                       \
        _Pragma("unroll")                                                     \
        for (int j = 0; j < 16; ++j) {                                        \
            const int e_ = 2 * wv + (j >> 3);                                 \
            const int c_ = j & 7;                                             \
            const f32x4* gsrc =                                               \
                w4 + (size_t)e_ * D4 + (kh_) * HALF + c_ * 64 + lane;         \
            __builtin_amdgcn_global_load_lds(                                 \
                (const __attribute__((address_space(1))) void*)gsrc,          \
                (__attribute__((address_space(3))) void*)&sw[e_][c_ * 64],    \
                16, 0, 0);                                                    \
        }                                                                     \
    } while (0)

    // g_ is the ABSOLUTE chunk index (0..15).
#define LOADH(dst, g_) do {                                                   \
        const int d4_ = (g_) * 64 + lane;                                     \
        _Pragma("unroll")                                                     \
        for (int t = 0; t < MT; ++t)                                          \
            dst[t] = __builtin_nontemporal_load(hb + (size_t)t * D4 + d4_);   \
    } while (0)

    // c_ is the PHASE-LOCAL chunk index (0..7) for the sw read.
#define COMPUTE(c_, hreg) do {                                                \
        _Pragma("unroll")                                                     \
        for (int e_ = 0; e_ < NEXP; ++e_) {                                   \
            f32x4 wvv = sw[e_][(c_) * 64 + lane];                             \
            _Pragma("unroll")                                                 \
            for (int t = 0; t < MT; ++t) {                                    \
                float a = acc[t * NEXP + e_];                                 \
                a = fmaf(hreg[t][0], wvv[0], a);                              \
                a = fmaf(hreg[t][1], wvv[1], a);                              \
                a = fmaf(hreg[t][2], wvv[2], a);                              \
                a = fmaf(hreg[t][3], wvv[3], a);                              \
                acc[t * NEXP + e_] = a;                                       \
            }                                                                 \
        }                                                                     \
    } while (0)

    // 3-buffer rotation, invariant at loop head: A = chunk kb+c, B = kb+c+1.
    // 2 triple-steps cover computes 0..5 and prefetch chunks kb+2..kb+7.
#define PHASELOOP(A, B, C, kb_) do {                                          \
        _Pragma("unroll 1")                                                   \
        for (int c = 0; c < NC - 2; c += 3) {                                 \
            LOADH(C, (kb_) + c + 2); COMPUTE(c + 0, A);                       \
            LOADH(A, (kb_) + c + 3); COMPUTE(c + 1, B);                       \
            LOADH(B, (kb_) + c + 4); COMPUTE(c + 2, C);                       \
        }                                                                     \
    } while (0)   /* after: A = kb+6, B = kb+7, C dead */

    f32x4 hv, hn, h2;   // silence -Wunused warnings pattern
    f32x4 bA[MT], bB[MT], bC[MT];
    (void)hv; (void)hn; (void)h2;

    // ---- Prologue: stage phase 0, preload chunks 0,1. ----
    STAGE(0);
    __builtin_amdgcn_sched_barrier(0);   // pin: stage before h loads
    LOADH(bA, 0);
    LOADH(bB, 1);
    // outstanding: 16 stage (older) + 16 h (newer); vmcnt(16) drains stage.
    asm volatile("s_waitcnt vmcnt(16)" ::: "memory");
    __builtin_amdgcn_s_barrier();
    asm volatile("" ::: "memory");
    __builtin_amdgcn_sched_barrier(0);

    // ---- Phase 0: free-run (no barriers). ----
    PHASELOOP(bA, bB, bC, 0);
    // Tail: compute 6,7 while prefetching phase 1's chunks 8,9.
    LOADH(bC, 8); COMPUTE(NC - 2, bA);
    LOADH(bA, 9); COMPUTE(NC - 1, bB);
    // Buffers now: bC = chunk 8, bA = chunk 9.

    // ---- Boundary: all waves done reading sw, restage, publish. ----
    asm volatile("s_waitcnt lgkmcnt(0)" ::: "memory");
    __builtin_amdgcn_s_barrier();
    asm volatile("" ::: "memory");
    STAGE(1);
    __builtin_amdgcn_sched_barrier(0);
    // Drain the stage (h chunks 8,9 were issued ~2 chunks ago; also drained,
    // harmlessly — they have long since arrived).
    asm volatile("s_waitcnt vmcnt(0)" ::: "memory");
    __builtin_amdgcn_s_barrier();
    asm volatile("" ::: "memory");
    __builtin_amdgcn_sched_barrier(0);

    // ---- Phase 1: free-run; initial pair is (bC, bA). ----
    PHASELOOP(bC, bA, bB, NC);
    COMPUTE(NC - 2, bC);   // chunk 14
    COMPUTE(NC - 1, bA);   // chunk 15

    // Two halving butterflies: acc[base..base+63] across 64 lanes -> lane l
    // owns flat index base+l (flat = j*16+e; token j = base/64*4 + (l>>4)).
#define BUTTERFLY(base) do {                                                  \
        _Pragma("unroll")                                                     \
        for (int b = 32; b >= 1; b >>= 1) {                                   \
            const bool hi_ = (lane & b) != 0;                                 \
            _Pragma("unroll")                                                 \
            for (int j = 0; j < b; ++j) {                                     \
                float lo_v = acc[(base) + j];                                 \
                float hi_v = acc[(base) + j + b];                             \
                float keepv = hi_ ? hi_v : lo_v;                              \
                float sendv = hi_ ? lo_v : hi_v;                              \
                acc[(base) + j] = keepv + __shfl_xor(sendv, b, 64);           \
            }                                                                 \
        }                                                                     \
    } while (0)

    BUTTERFLY(0);
    BUTTERFLY(64);
    const float logit0 = acc[0];    // token t0 + (lane>>4),     expert lane&15
    const float logit1 = acc[64];   // token t0 + 4 + (lane>>4), expert lane&15

    // Top-2 within each 16-lane group, tie-break low index (lax.top_k order).
    const int eidx = lane & 15;
#define TOP2_WRITE(logit_, tok_) do {                                         \
        float m1 = (logit_); int i1 = eidx;                                   \
        _Pragma("unroll")                                                     \
        for (int s = 1; s < 16; s <<= 1) {                                    \
            float ov = __shfl_xor(m1, s, 64);                                 \
            int   oi = __shfl_xor(i1, s, 64);                                 \
            if (ov > m1 || (ov == m1 && oi < i1)) { m1 = ov; i1 = oi; }       \
        }                                                                     \
        float masked = (eidx == i1) ? -INFINITY : (logit_);                   \
        float m2 = masked; int i2 = eidx;                                     \
        _Pragma("unroll")                                                     \
        for (int s = 1; s < 16; s <<= 1) {                                    \
            float ov = __shfl_xor(m2, s, 64);                                 \
            int   oi = __shfl_xor(i2, s, 64);                                 \
            if (ov > m2 || (ov == m2 && oi < i2)) { m2 = ov; i2 = oi; }       \
        }                                                                     \
        if (eidx == 0) {                                                      \
            const float r_ = expf(m2 - m1);                                   \
            const float s_ = 1.0f / (1.0f + r_);                              \
            float2* oidx = reinterpret_cast<float2*>(out);                    \
            float2* owt  = reinterpret_cast<float2*>(out + 2 * T_TOKENS);     \
            oidx[tok_] = make_float2((float)i1, (float)i2);                   \
            owt[tok_]  = make_float2(s_, r_ * s_);                            \
        }                                                                     \
    } while (0)

    TOP2_WRITE(logit0, t0 + (lane >> 4));
    TOP2_WRITE(logit1, t0 + 4 + (lane >> 4));

#undef STAGE
#undef LOADH
#undef COMPUTE
#undef PHASELOOP
#undef BUTTERFLY
#undef TOP2_WRITE
}

extern "C" void kernel_launch(void* const* d_in, const int* in_sizes, int n_in,
                              void* d_out, int out_size, void* d_ws, size_t ws_size,
                              hipStream_t stream) {
    const float* h = (const float*)d_in[0];   // hidden_states [32768, 4096] f32
    const float* w = (const float*)d_in[1];   // wg_weight [16, 4096] f32
    float* out = (float*)d_out;               // [65536 idx-as-f32][65536 weights]

    const int blocks = T_TOKENS / (MT * WAVES);   // 512 blocks, 512 thr
    moe_gate_kernel<<<blocks, 512, 0, stream>>>(h, w, out);
}

// Round 7
// 198.652 us; speedup vs baseline: 1.2881x; 1.2881x over previous
//
#include <hip/hip_runtime.h>
#include <math.h>

// Problem constants (fixed by setup_inputs)
#define T_TOKENS 32768
#define NEXP     16
#define HID      4096
#define MT       4            // tokens per wave (acc = 64/lane)
#define WAVES    8            // waves per block -> 32 tokens/block
#define D4       (HID / 4)    // 1024 f32x4 per row
#define HALF     (D4 / 2)     // 512 f32x4 per half-row
#define NC       (HALF / 64)  // 8 chunks per phase; 16 global chunks

typedef float f32x4 __attribute__((ext_vector_type(4)));

// R5 structure (two-phase 128KiB mega-stage, 3 sync points, free-running
// phases) + depth-3 h prefetch: 4 rotating register buffers keep ~12 KiB in
// flight per wave (96 KiB/CU vs R5's 64) without spilling: MT=4 frees the
// VGPRs that R6's MT=8 attempt spilled over (acc 64 + bufs 64 + addr ~170).
__global__ __launch_bounds__(512, 2) void moe_gate_kernel(
    const float* __restrict__ h,   // [T, HID]
    const float* __restrict__ w,   // [NEXP, HID]
    float* __restrict__ out)       // [2*T] indices (as float), then [2*T] weights
{
    __shared__ f32x4 sw[NEXP][HALF];               // 128 KiB, single-buffered

    const int lane = threadIdx.x & 63;
    const int wv   = threadIdx.x >> 6;             // wave id (0..7)
    const int t0   = blockIdx.x * (MT * WAVES) + wv * MT;
    const int t0u  = __builtin_amdgcn_readfirstlane(t0);   // wave-uniform
    const f32x4* __restrict__ hb =
        reinterpret_cast<const f32x4*>(h + (size_t)t0u * HID);
    const f32x4* __restrict__ w4 = reinterpret_cast<const f32x4*>(w);

    float acc[MT * NEXP];                          // 64 accumulators
    #pragma unroll
    for (int i = 0; i < MT * NEXP; ++i) acc[i] = 0.0f;

    // Wave wv stages experts 2wv,2wv+1 (8 chunks each = 16 gll of 1 KiB).
#define STAGE(kh_) do {                                                       \
        _Pragma("unroll")                                                     \
        for (int j = 0; j < 16; ++j) {                                        \
            const int e_ = 2 * wv + (j >> 3);                                 \
            const int c_ = j & 7;                                             \
            const f32x4* gsrc =                                               \
                w4 + (size_t)e_ * D4 + (kh_) * HALF + c_ * 64 + lane;         \
            __builtin_amdgcn_global_load_lds(                                 \
                (const __attribute__((address_space(1))) void*)gsrc,          \
                (__attribute__((address_space(3))) void*)&sw[e_][c_ * 64],    \
                16, 0, 0);                                                    \
        }                                                                     \
    } while (0)

    // g_ = ABSOLUTE chunk index (0..15); 4 loads of 16 B.
#define LOADH(dst, g_) do {                                                   \
        const int d4_ = (g_) * 64 + lane;                                     \
        _Pragma("unroll")                                                     \
        for (int t = 0; t < MT; ++t)                                          \
            dst[t] = __builtin_nontemporal_load(hb + (size_t)t * D4 + d4_);   \
    } while (0)

    // l_ = PHASE-LOCAL chunk index (0..7) for the sw read.
#define COMPUTE(l_, hreg) do {                                                \
        _Pragma("unroll")                                                     \
        for (int e_ = 0; e_ < NEXP; ++e_) {                                   \
            f32x4 wvv = sw[e_][(l_) * 64 + lane];                             \
            _Pragma("unroll")                                                 \
            for (int t = 0; t < MT; ++t) {                                    \
                float a = acc[t * NEXP + e_];                                 \
                a = fmaf(hreg[t][0], wvv[0], a);                              \
                a = fmaf(hreg[t][1], wvv[1], a);                              \
                a = fmaf(hreg[t][2], wvv[2], a);                              \
                a = fmaf(hreg[t][3], wvv[3], a);                              \
                acc[t * NEXP + e_] = a;                                       \
            }                                                                 \
        }                                                                     \
    } while (0)

    // Depth-3 rotation. Entry invariant: A=g, B=g+1, C=g+2 in flight/arrived.
    // Exit: A=g+4, B=g+5, C=g+6. During each compute, 3 chunks are in flight.
#define GROUP(A, B, C, D, g_, l_) do {                                        \
        LOADH(D, (g_) + 3); COMPUTE((l_) + 0, A);                             \
        LOADH(A, (g_) + 4); COMPUTE((l_) + 1, B);                             \
        LOADH(B, (g_) + 5); COMPUTE((l_) + 2, C);                             \
        LOADH(C, (g_) + 6); COMPUTE((l_) + 3, D);                             \
    } while (0)

    f32x4 bA[MT], bB[MT], bC[MT], bD[MT];

    // ---- Prologue: stage phase 0; preload chunks 0,1,2. ----
    STAGE(0);
    __builtin_amdgcn_sched_barrier(0);   // pin: stage strictly before h loads
    LOADH(bA, 0);
    LOADH(bB, 1);
    LOADH(bC, 2);
    __builtin_amdgcn_sched_barrier(0);
    // outstanding = 16 stage (oldest) + 12 h (newest); vmcnt(12) drains the
    // stage completely while keeping all 12 h loads in flight.
    asm volatile("s_waitcnt vmcnt(12)" ::: "memory");
    __builtin_amdgcn_s_barrier();
    asm volatile("" ::: "memory");
    __builtin_amdgcn_sched_barrier(0);

    // ---- Phase 0: free-run, chunks 0..7 (h prefetch reaches chunk 10). ----
    #pragma unroll 1
    for (int c = 0; c < NC; c += 4)
        GROUP(bA, bB, bC, bD, c, c);
    // Exit: bA=8, bB=9, bC=10 in flight (phase-1 chunks, legal: h is
    // independent of the stage).

    // ---- Boundary: everyone done reading sw -> restage -> publish. ----
    asm volatile("s_waitcnt lgkmcnt(0)" ::: "memory");
    __builtin_amdgcn_s_barrier();
    asm volatile("" ::: "memory");
    STAGE(1);
    __builtin_amdgcn_sched_barrier(0);
    // Full drain: stage must be complete. (Also drains h 8..10 — they were
    // issued a full group earlier and have effectively arrived.)
    asm volatile("s_waitcnt vmcnt(0)" ::: "memory");
    __builtin_amdgcn_s_barrier();
    asm volatile("" ::: "memory");
    __builtin_amdgcn_sched_barrier(0);

    // ---- Phase 1: chunks 8..15 (local 0..7). ----
    GROUP(bA, bB, bC, bD, 8, 0);         // computes 8..11, loads 11..14
    LOADH(bD, 15);
    COMPUTE(4, bA);                      // chunk 12
    COMPUTE(5, bB);                      // chunk 13
    COMPUTE(6, bC);                      // chunk 14
    COMPUTE(7, bD);                      // chunk 15

    // Halving butterfly: 64 accumulators across 64 lanes -> lane l owns flat
    // index l (token t0 + (l>>4), expert l&15).
    #pragma unroll
    for (int b = 32; b >= 1; b >>= 1) {
        const bool hi_ = (lane & b) != 0;
        #pragma unroll
        for (int j = 0; j < b; ++j) {
            float lo_v = acc[j];
            float hi_v = acc[j + b];
            float keepv = hi_ ? hi_v : lo_v;   // compile-time indices only
            float sendv = hi_ ? lo_v : hi_v;
            acc[j] = keepv + __shfl_xor(sendv, b, 64);
        }
    }
    const float logit = acc[0];

    // Top-2 within each 16-lane group, tie-break low index (lax.top_k order).
    const int eidx = lane & 15;
    float m1 = logit; int i1 = eidx;
    #pragma unroll
    for (int s = 1; s < 16; s <<= 1) {
        float ov = __shfl_xor(m1, s, 64);
        int   oi = __shfl_xor(i1, s, 64);
        if (ov > m1 || (ov == m1 && oi < i1)) { m1 = ov; i1 = oi; }
    }
    float masked = (eidx == i1) ? -INFINITY : logit;
    float m2 = masked; int i2 = eidx;
    #pragma unroll
    for (int s = 1; s < 16; s <<= 1) {
        float ov = __shfl_xor(m2, s, 64);
        int   oi = __shfl_xor(i2, s, 64);
        if (ov > m2 || (ov == m2 && oi < i2)) { m2 = ov; i2 = oi; }
    }

    if (eidx == 0) {
        const int t = t0 + (lane >> 4);
        // softmax denom cancels in renorm: w1 = 1/(1+e^(l2-l1)), l2-l1 <= 0.
        const float r  = expf(m2 - m1);
        const float s  = 1.0f / (1.0f + r);
        float2* oidx = reinterpret_cast<float2*>(out);
        float2* owt  = reinterpret_cast<float2*>(out + 2 * T_TOKENS);
        oidx[t] = make_float2((float)i1, (float)i2);
        owt[t]  = make_float2(s, r * s);
    }
#undef STAGE
#undef LOADH
#undef COMPUTE
#undef GROUP
}

extern "C" void kernel_launch(void* const* d_in, const int* in_sizes, int n_in,
                              void* d_out, int out_size, void* d_ws, size_t ws_size,
                              hipStream_t stream) {
    const float* h = (const float*)d_in[0];   // hidden_states [32768, 4096] f32
    const float* w = (const float*)d_in[1];   // wg_weight [16, 4096] f32
    float* out = (float*)d_out;               // [65536 idx-as-f32][65536 weights]

    const int blocks = T_TOKENS / (MT * WAVES);   // 1024 blocks, 512 thr
    moe_gate_kernel<<<blocks, 512, 0, stream>>>(h, w, out);
}

// Round 8
// 119.648 us; speedup vs baseline: 2.1386x; 1.6603x over previous
//
#include <hip/hip_runtime.h>
#include <math.h>

// Problem constants (fixed by setup_inputs)
#define T_TOKENS 32768
#define NEXP     16
#define HID      4096
#define MT       4            // tokens per wave (acc = 64/lane, VGPR <= 128)
#define WAVES    8            // waves per block -> 32 tokens/block
#define D4       (HID / 4)    // 1024 f32x4 per row
#define QTR      (D4 / 4)     // 256 f32x4 per quarter-row
#define NCP      (QTR / 64)   // 4 chunks per phase
#define NPH      4            // 4 phases

typedef float f32x4 __attribute__((ext_vector_type(4)));

// R5's proven depth-1 inner loop, with the stage shrunk to a QUARTER of w
// (64 KiB LDS) so 2 blocks co-reside per CU: 16 waves/CU = 4 waves/SIMD,
// doubling TLP vs R5 (the copy kernels that hit ~6.3 TB/s rely on TLP, not
// per-wave queue depth — R6/R7 showed depth games regress). VGPR forced
// <=128 via launch_bounds(512,4) + MT=4.
__global__ __launch_bounds__(512, 4) void moe_gate_kernel(
    const float* __restrict__ h,   // [T, HID]
    const float* __restrict__ w,   // [NEXP, HID]
    float* __restrict__ out)       // [2*T] indices (as float), then [2*T] weights
{
    __shared__ f32x4 sw[NEXP][QTR];                // 64 KiB, single-buffered

    const int lane = threadIdx.x & 63;
    const int wv   = threadIdx.x >> 6;             // wave id (0..7)
    const int t0   = blockIdx.x * (MT * WAVES) + wv * MT;
    const int t0u  = __builtin_amdgcn_readfirstlane(t0);   // wave-uniform
    const f32x4* __restrict__ hb =
        reinterpret_cast<const f32x4*>(h + (size_t)t0u * HID);
    const f32x4* __restrict__ w4 = reinterpret_cast<const f32x4*>(w);

    float acc[MT * NEXP];                          // 64 accumulators
    #pragma unroll
    for (int i = 0; i < MT * NEXP; ++i) acc[i] = 0.0f;

    // Wave wv stages experts 2wv,2wv+1, chunks 0..3 of quarter p_ (8 gll).
#define STAGE(p_) do {                                                        \
        _Pragma("unroll")                                                     \
        for (int j = 0; j < 8; ++j) {                                         \
            const int e_ = 2 * wv + (j >> 2);                                 \
            const int c_ = j & 3;                                             \
            const f32x4* gsrc =                                               \
                w4 + (size_t)e_ * D4 + (p_) * QTR + c_ * 64 + lane;           \
            __builtin_amdgcn_global_load_lds(                                 \
                (const __attribute__((address_space(1))) void*)gsrc,          \
                (__attribute__((address_space(3))) void*)&sw[e_][c_ * 64],    \
                16, 0, 0);                                                    \
        }                                                                     \
    } while (0)

    // g_ = ABSOLUTE chunk index (0..15); 4 loads of 16 B.
#define LOADH(dst, g_) do {                                                   \
        const int d4_ = (g_) * 64 + lane;                                     \
        _Pragma("unroll")                                                     \
        for (int t = 0; t < MT; ++t)                                          \
            dst[t] = __builtin_nontemporal_load(hb + (size_t)t * D4 + d4_);   \
    } while (0)

    // l_ = PHASE-LOCAL chunk index (0..3) for the sw read.
#define COMPUTE(l_, hreg) do {                                                \
        _Pragma("unroll")                                                     \
        for (int e_ = 0; e_ < NEXP; ++e_) {                                   \
            f32x4 wvv = sw[e_][(l_) * 64 + lane];                             \
            _Pragma("unroll")                                                 \
            for (int t = 0; t < MT; ++t) {                                    \
                float a = acc[t * NEXP + e_];                                 \
                a = fmaf(hreg[t][0], wvv[0], a);                              \
                a = fmaf(hreg[t][1], wvv[1], a);                              \
                a = fmaf(hreg[t][2], wvv[2], a);                              \
                a = fmaf(hreg[t][3], wvv[3], a);                              \
                acc[t * NEXP + e_] = a;                                       \
            }                                                                 \
        }                                                                     \
    } while (0)

    f32x4 hv[MT], hn[MT];

    #pragma unroll 1
    for (int p = 0; p < NPH; ++p) {
        if (p) {
            // All waves done READING sw (previous phase) before restaging.
            asm volatile("s_waitcnt lgkmcnt(0)" ::: "memory");
            __builtin_amdgcn_s_barrier();
            asm volatile("" ::: "memory");
        }
        STAGE(p);
        __builtin_amdgcn_sched_barrier(0);   // pin: stage strictly before h
        LOADH(hv, 4 * p);
        __builtin_amdgcn_sched_barrier(0);
        // outstanding = 8 stage (older) + 4 h (newer); vmcnt(4) drains the
        // stage completely while keeping the 4 h loads in flight.
        asm volatile("s_waitcnt vmcnt(4)" ::: "memory");
        __builtin_amdgcn_s_barrier();
        asm volatile("" ::: "memory");
        __builtin_amdgcn_sched_barrier(0);

        // Free-run: depth-1 prefetch, R5's exact proven shape.
        #pragma unroll 1
        for (int c = 0; c < NCP - 1; ++c) {
            LOADH(hn, 4 * p + c + 1);
            COMPUTE(c, hv);
            #pragma unroll
            for (int t = 0; t < MT; ++t) hv[t] = hn[t];
        }
        COMPUTE(NCP - 1, hv);
    }

    // Halving butterfly: 64 accumulators across 64 lanes -> lane l owns flat
    // index l (token t0 + (l>>4), expert l&15).
    #pragma unroll
    for (int b = 32; b >= 1; b >>= 1) {
        const bool hi_ = (lane & b) != 0;
        #pragma unroll
        for (int j = 0; j < b; ++j) {
            float lo_v = acc[j];
            float hi_v = acc[j + b];
            float keepv = hi_ ? hi_v : lo_v;   // compile-time indices only
            float sendv = hi_ ? lo_v : hi_v;
            acc[j] = keepv + __shfl_xor(sendv, b, 64);
        }
    }
    const float logit = acc[0];

    // Top-2 within each 16-lane group, tie-break low index (lax.top_k order).
    const int eidx = lane & 15;
    float m1 = logit; int i1 = eidx;
    #pragma unroll
    for (int s = 1; s < 16; s <<= 1) {
        float ov = __shfl_xor(m1, s, 64);
        int   oi = __shfl_xor(i1, s, 64);
        if (ov > m1 || (ov == m1 && oi < i1)) { m1 = ov; i1 = oi; }
    }
    float masked = (eidx == i1) ? -INFINITY : logit;
    float m2 = masked; int i2 = eidx;
    #pragma unroll
    for (int s = 1; s < 16; s <<= 1) {
        float ov = __shfl_xor(m2, s, 64);
        int   oi = __shfl_xor(i2, s, 64);
        if (ov > m2 || (ov == m2 && oi < i2)) { m2 = ov; i2 = oi; }
    }

    if (eidx == 0) {
        const int t = t0 + (lane >> 4);
        // softmax denom cancels in renorm: w1 = 1/(1+e^(l2-l1)), l2-l1 <= 0.
        const float r  = expf(m2 - m1);
        const float s  = 1.0f / (1.0f + r);
        float2* oidx = reinterpret_cast<float2*>(out);
        float2* owt  = reinterpret_cast<float2*>(out + 2 * T_TOKENS);
        oidx[t] = make_float2((float)i1, (float)i2);
        owt[t]  = make_float2(s, r * s);
    }
#undef STAGE
#undef LOADH
#undef COMPUTE
}

extern "C" void kernel_launch(void* const* d_in, const int* in_sizes, int n_in,
                              void* d_out, int out_size, void* d_ws, size_t ws_size,
                              hipStream_t stream) {
    const float* h = (const float*)d_in[0];   // hidden_states [32768, 4096] f32
    const float* w = (const float*)d_in[1];   // wg_weight [16, 4096] f32
    float* out = (float*)d_out;               // [65536 idx-as-f32][65536 weights]

    const int blocks = T_TOKENS / (MT * WAVES);   // 1024 blocks, 512 thr
    moe_gate_kernel<<<blocks, 512, 0, stream>>>(h, w, out);
}

// Round 9
// 116.070 us; speedup vs baseline: 2.2046x; 1.0308x over previous
//
#include <hip/hip_runtime.h>
#include <math.h>

// Problem constants (fixed by setup_inputs)
#define T_TOKENS 32768
#define NEXP     16
#define HID      4096
#define MT       8            // tokens per wave
#define WAVES    8            // waves per block -> 64 tokens/block
#define D4       (HID / 4)    // 1024 f32x4 per row
#define HALF     (D4 / 2)     // 512 f32x4 per half-row
#define NC       (HALF / 64)  // 8 chunk-iterations per phase

typedef float f32x4 __attribute__((ext_vector_type(4)));

// R5 (best: 112.9 us) with ONE change: plain loads for h instead of
// __builtin_nontemporal_load. NT suppresses L2 allocation; if that weakens
// the L2's MSHR/read-combining role it caps sustained outstanding reads —
// matching the observed 4.76 TB/s plateau that was insensitive to wave-side
// depth (R6/R7) and TLP (R8). m13's 6.3 TB/s copy + m146's 4.89 TB/s
// RMSNorm both use plain loads.
__global__ __launch_bounds__(512, 2) void moe_gate_kernel(
    const float* __restrict__ h,   // [T, HID]
    const float* __restrict__ w,   // [NEXP, HID]
    float* __restrict__ out)       // [2*T] indices (as float), then [2*T] weights
{
    __shared__ f32x4 sw[NEXP][HALF];               // 128 KiB, single-buffered

    const int lane = threadIdx.x & 63;
    const int wv   = threadIdx.x >> 6;             // wave id (0..7)
    const int t0   = blockIdx.x * (MT * WAVES) + wv * MT;
    const int t0u  = __builtin_amdgcn_readfirstlane(t0);   // wave-uniform
    const f32x4* __restrict__ hb =
        reinterpret_cast<const f32x4*>(h + (size_t)t0u * HID);
    const f32x4* __restrict__ w4 = reinterpret_cast<const f32x4*>(w);

    float acc[MT * NEXP];
    #pragma unroll
    for (int i = 0; i < MT * NEXP; ++i) acc[i] = 0.0f;

    // Wave wv stages experts 2wv,2wv+1 (8 chunks each = 16 loads of 1 KiB).
#define STAGE(kh_) do {                                                       \
        _Pragma("unroll")                                                     \
        for (int j = 0; j < 16; ++j) {                                        \
            const int e_ = 2 * wv + (j >> 3);                                 \
            const int c_ = j & 7;                                             \
            const f32x4* gsrc =                                               \
                w4 + (size_t)e_ * D4 + (kh_) * HALF + c_ * 64 + lane;         \
            __builtin_amdgcn_global_load_lds(                                 \
                (const __attribute__((address_space(1))) void*)gsrc,          \
                (__attribute__((address_space(3))) void*)&sw[e_][c_ * 64],    \
                16, 0, 0);                                                    \
        }                                                                     \
    } while (0)

    // ONLY change vs R5: plain (cached) loads, no NT hint.
#define LOADH(dst, kh_, c_) do {                                              \
        const int d4_ = (kh_) * HALF + (c_) * 64 + lane;                      \
        _Pragma("unroll")                                                     \
        for (int t = 0; t < MT; ++t)                                          \
            dst[t] = hb[(size_t)t * D4 + d4_];                                \
    } while (0)

#define COMPUTE(c_, hreg) do {                                                \
        _Pragma("unroll")                                                     \
        for (int e_ = 0; e_ < NEXP; ++e_) {                                   \
            f32x4 wvv = sw[e_][(c_) * 64 + lane];                             \
            _Pragma("unroll")                                                 \
            for (int t = 0; t < MT; ++t) {                                    \
                float a = acc[t * NEXP + e_];                                 \
                a = fmaf(hreg[t][0], wvv[0], a);                              \
                a = fmaf(hreg[t][1], wvv[1], a);                              \
                a = fmaf(hreg[t][2], wvv[2], a);                              \
                a = fmaf(hreg[t][3], wvv[3], a);                              \
                acc[t * NEXP + e_] = a;                                       \
            }                                                                 \
        }                                                                     \
    } while (0)

    f32x4 hv[MT], hn[MT];

    for (int kh = 0; kh < 2; ++kh) {
        if (kh) {
            // All waves must be done READING sw (phase 0) before restaging.
            asm volatile("s_waitcnt lgkmcnt(0)" ::: "memory");
            __builtin_amdgcn_s_barrier();
            asm volatile("" ::: "memory");
        }
        STAGE(kh);
        __builtin_amdgcn_sched_barrier(0);   // pin: stage strictly before h
        LOADH(hv, kh, 0);
        // outstanding: 16 stage (older) + 8 h (newer); vmcnt(8) drains the
        // stage completely while keeping h(c=0) in flight.
        asm volatile("s_waitcnt vmcnt(8)" ::: "memory");
        __builtin_amdgcn_s_barrier();
        asm volatile("" ::: "memory");
        __builtin_amdgcn_sched_barrier(0);

        // Free-running phase: no barriers, no asm waits. 1-chunk h prefetch;
        // compiler schedules loads/ds_reads/FMAs at will.
        #pragma unroll 1
        for (int c = 0; c < NC - 1; ++c) {
            LOADH(hn, kh, c + 1);
            COMPUTE(c, hv);
            #pragma unroll
            for (int t = 0; t < MT; ++t) hv[t] = hn[t];
        }
        COMPUTE(NC - 1, hv);
    }

    // Two halving butterflies: acc[base..base+63] across 64 lanes -> lane l
    // owns flat index base+l (flat = j*16+e; token j = base/64*4 + (l>>4)).
#define BUTTERFLY(base) do {                                                  \
        _Pragma("unroll")                                                     \
        for (int b = 32; b >= 1; b >>= 1) {                                   \
            const bool hi_ = (lane & b) != 0;                                 \
            _Pragma("unroll")                                                 \
            for (int j = 0; j < b; ++j) {                                     \
                float lo_v = acc[(base) + j];                                 \
                float hi_v = acc[(base) + j + b];                             \
                float keepv = hi_ ? hi_v : lo_v;                              \
                float sendv = hi_ ? lo_v : hi_v;                              \
                acc[(base) + j] = keepv + __shfl_xor(sendv, b, 64);           \
            }                                                                 \
        }                                                                     \
    } while (0)

    BUTTERFLY(0);
    BUTTERFLY(64);
    const float logit0 = acc[0];    // token t0 + (lane>>4),     expert lane&15
    const float logit1 = acc[64];   // token t0 + 4 + (lane>>4), expert lane&15

    // Top-2 within each 16-lane group, tie-break low index (lax.top_k order).
    const int eidx = lane & 15;
#define TOP2_WRITE(logit_, tok_) do {                                         \
        float m1 = (logit_); int i1 = eidx;                                   \
        _Pragma("unroll")                                                     \
        for (int s = 1; s < 16; s <<= 1) {                                    \
            float ov = __shfl_xor(m1, s, 64);                                 \
            int   oi = __shfl_xor(i1, s, 64);                                 \
            if (ov > m1 || (ov == m1 && oi < i1)) { m1 = ov; i1 = oi; }       \
        }                                                                     \
        float masked = (eidx == i1) ? -INFINITY : (logit_);                   \
        float m2 = masked; int i2 = eidx;                                     \
        _Pragma("unroll")                                                     \
        for (int s = 1; s < 16; s <<= 1) {                                    \
            float ov = __shfl_xor(m2, s, 64);                                 \
            int   oi = __shfl_xor(i2, s, 64);                                 \
            if (ov > m2 || (ov == m2 && oi < i2)) { m2 = ov; i2 = oi; }       \
        }                                                                     \
        if (eidx == 0) {                                                      \
            const float r_ = expf(m2 - m1);                                   \
            const float s_ = 1.0f / (1.0f + r_);                              \
            float2* oidx = reinterpret_cast<float2*>(out);                    \
            float2* owt  = reinterpret_cast<float2*>(out + 2 * T_TOKENS);     \
            oidx[tok_] = make_float2((float)i1, (float)i2);                   \
            owt[tok_]  = make_float2(s_, r_ * s_);                            \
        }                                                                     \
    } while (0)

    TOP2_WRITE(logit0, t0 + (lane >> 4));
    TOP2_WRITE(logit1, t0 + 4 + (lane >> 4));

#undef STAGE
#undef LOADH
#undef COMPUTE
#undef BUTTERFLY
#undef TOP2_WRITE
}

extern "C" void kernel_launch(void* const* d_in, const int* in_sizes, int n_in,
                              void* d_out, int out_size, void* d_ws, size_t ws_size,
                              hipStream_t stream) {
    const float* h = (const float*)d_in[0];   // hidden_states [32768, 4096] f32
    const float* w = (const float*)d_in[1];   // wg_weight [16, 4096] f32
    float* out = (float*)d_out;               // [65536 idx-as-f32][65536 weights]

    const int blocks = T_TOKENS / (MT * WAVES);   // 512 blocks, 512 thr
    moe_gate_kernel<<<blocks, 512, 0, stream>>>(h, w, out);
}

// Round 10
// 108.648 us; speedup vs baseline: 2.3551x; 1.0683x over previous
//
#include <hip/hip_runtime.h>
#include <math.h>

// Problem constants (fixed by setup_inputs)
#define T_TOKENS 32768
#define NEXP     16
#define HID      4096
#define MT       8            // tokens per wave
#define WAVES    8            // waves per block -> 64 tokens/block
#define D4       (HID / 4)    // 1024 f32x4 per row
#define HALF     (D4 / 2)     // 512 f32x4 per half-row
#define NC       (HALF / 64)  // 8 chunk-iterations per phase

typedef float f32x4 __attribute__((ext_vector_type(4)));

// FINAL (R5 verbatim — session best, 112.9 us = 4.76 TB/s pure-read).
// Structure: two-phase mega-stage — LDS holds w for ALL 16 experts over half
// the hidden dim (128 KiB); per phase, waves free-run 8 chunk-iterations
// with NO barriers/asm waits; only 3 sync points per block. h streamed with
// depth-1 register prefetch + NT hint (A/B'd vs plain in R9: NT better).
// Refuted alternatives: deeper prefetch (R6/R7), 2 blocks/CU TLP (R8),
// per-iter counted-vmcnt pipeline (R3), MT-amplification (R4 null).
__global__ __launch_bounds__(512, 2) void moe_gate_kernel(
    const float* __restrict__ h,   // [T, HID]
    const float* __restrict__ w,   // [NEXP, HID]
    float* __restrict__ out)       // [2*T] indices (as float), then [2*T] weights
{
    __shared__ f32x4 sw[NEXP][HALF];               // 128 KiB, single-buffered

    const int lane = threadIdx.x & 63;
    const int wv   = threadIdx.x >> 6;             // wave id (0..7)
    const int t0   = blockIdx.x * (MT * WAVES) + wv * MT;
    const int t0u  = __builtin_amdgcn_readfirstlane(t0);   // wave-uniform
    const f32x4* __restrict__ hb =
        reinterpret_cast<const f32x4*>(h + (size_t)t0u * HID);
    const f32x4* __restrict__ w4 = reinterpret_cast<const f32x4*>(w);

    float acc[MT * NEXP];
    #pragma unroll
    for (int i = 0; i < MT * NEXP; ++i) acc[i] = 0.0f;

    // Wave wv stages experts 2wv,2wv+1 (8 chunks each = 16 loads of 1 KiB).
#define STAGE(kh_) do {                                                       \
        _Pragma("unroll")                                                     \
        for (int j = 0; j < 16; ++j) {                                        \
            const int e_ = 2 * wv + (j >> 3);                                 \
            const int c_ = j & 7;                                             \
            const f32x4* gsrc =                                               \
                w4 + (size_t)e_ * D4 + (kh_) * HALF + c_ * 64 + lane;         \
            __builtin_amdgcn_global_load_lds(                                 \
                (const __attribute__((address_space(1))) void*)gsrc,          \
                (__attribute__((address_space(3))) void*)&sw[e_][c_ * 64],    \
                16, 0, 0);                                                    \
        }                                                                     \
    } while (0)

#define LOADH(dst, kh_, c_) do {                                              \
        const int d4_ = (kh_) * HALF + (c_) * 64 + lane;                      \
        _Pragma("unroll")                                                     \
        for (int t = 0; t < MT; ++t)                                          \
            dst[t] = __builtin_nontemporal_load(hb + (size_t)t * D4 + d4_);   \
    } while (0)

#define COMPUTE(c_, hreg) do {                                                \
        _Pragma("unroll")                                                     \
        for (int e_ = 0; e_ < NEXP; ++e_) {                                   \
            f32x4 wvv = sw[e_][(c_) * 64 + lane];                             \
            _Pragma("unroll")                                                 \
            for (int t = 0; t < MT; ++t) {                                    \
                float a = acc[t * NEXP + e_];                                 \
                a = fmaf(hreg[t][0], wvv[0], a);                              \
                a = fmaf(hreg[t][1], wvv[1], a);                              \
                a = fmaf(hreg[t][2], wvv[2], a);                              \
                a = fmaf(hreg[t][3], wvv[3], a);                              \
                acc[t * NEXP + e_] = a;                                       \
            }                                                                 \
        }                                                                     \
    } while (0)

    f32x4 hv[MT], hn[MT];

    for (int kh = 0; kh < 2; ++kh) {
        if (kh) {
            // All waves must be done READING sw (phase 0) before restaging.
            asm volatile("s_waitcnt lgkmcnt(0)" ::: "memory");
            __builtin_amdgcn_s_barrier();
            asm volatile("" ::: "memory");
        }
        STAGE(kh);
        __builtin_amdgcn_sched_barrier(0);   // pin: stage strictly before h
        LOADH(hv, kh, 0);
        // outstanding: 16 stage (older) + 8 h (newer); vmcnt(8) drains the
        // stage completely while keeping h(c=0) in flight.
        asm volatile("s_waitcnt vmcnt(8)" ::: "memory");
        __builtin_amdgcn_s_barrier();
        asm volatile("" ::: "memory");
        __builtin_amdgcn_sched_barrier(0);

        // Free-running phase: no barriers, no asm waits. 1-chunk h prefetch;
        // compiler schedules loads/ds_reads/FMAs at will.
        #pragma unroll 1
        for (int c = 0; c < NC - 1; ++c) {
            LOADH(hn, kh, c + 1);
            COMPUTE(c, hv);
            #pragma unroll
            for (int t = 0; t < MT; ++t) hv[t] = hn[t];
        }
        COMPUTE(NC - 1, hv);
    }

    // Two halving butterflies: acc[base..base+63] across 64 lanes -> lane l
    // owns flat index base+l (flat = j*16+e; token j = base/64*4 + (l>>4)).
#define BUTTERFLY(base) do {                                                  \
        _Pragma("unroll")                                                     \
        for (int b = 32; b >= 1; b >>= 1) {                                   \
            const bool hi_ = (lane & b) != 0;                                 \
            _Pragma("unroll")                                                 \
            for (int j = 0; j < b; ++j) {                                     \
                float lo_v = acc[(base) + j];                                 \
                float hi_v = acc[(base) + j + b];                             \
                float keepv = hi_ ? hi_v : lo_v;                              \
                float sendv = hi_ ? lo_v : hi_v;                              \
                acc[(base) + j] = keepv + __shfl_xor(sendv, b, 64);           \
            }                                                                 \
        }                                                                     \
    } while (0)

    BUTTERFLY(0);
    BUTTERFLY(64);
    const float logit0 = acc[0];    // token t0 + (lane>>4),     expert lane&15
    const float logit1 = acc[64];   // token t0 + 4 + (lane>>4), expert lane&15

    // Top-2 within each 16-lane group, tie-break low index (lax.top_k order).
    const int eidx = lane & 15;
#define TOP2_WRITE(logit_, tok_) do {                                         \
        float m1 = (logit_); int i1 = eidx;                                   \
        _Pragma("unroll")                                                     \
        for (int s = 1; s < 16; s <<= 1) {                                    \
            float ov = __shfl_xor(m1, s, 64);                                 \
            int   oi = __shfl_xor(i1, s, 64);                                 \
            if (ov > m1 || (ov == m1 && oi < i1)) { m1 = ov; i1 = oi; }       \
        }                                                                     \
        float masked = (eidx == i1) ? -INFINITY : (logit_);                   \
        float m2 = masked; int i2 = eidx;                                     \
        _Pragma("unroll")                                                     \
        for (int s = 1; s < 16; s <<= 1) {                                    \
            float ov = __shfl_xor(m2, s, 64);                                 \
            int   oi = __shfl_xor(i2, s, 64);                                 \
            if (ov > m2 || (ov == m2 && oi < i2)) { m2 = ov; i2 = oi; }       \
        }                                                                     \
        if (eidx == 0) {                                                      \
            const float r_ = expf(m2 - m1);                                   \
            const float s_ = 1.0f / (1.0f + r_);                              \
            float2* oidx = reinterpret_cast<float2*>(out);                    \
            float2* owt  = reinterpret_cast<float2*>(out + 2 * T_TOKENS);     \
            oidx[tok_] = make_float2((float)i1, (float)i2);                   \
            owt[tok_]  = make_float2(s_, r_ * s_);                            \
        }                                                                     \
    } while (0)

    TOP2_WRITE(logit0, t0 + (lane >> 4));
    TOP2_WRITE(logit1, t0 + 4 + (lane >> 4));

#undef STAGE
#undef LOADH
#undef COMPUTE
#undef BUTTERFLY
#undef TOP2_WRITE
}

extern "C" void kernel_launch(void* const* d_in, const int* in_sizes, int n_in,
                              void* d_out, int out_size, void* d_ws, size_t ws_size,
                              hipStream_t stream) {
    const float* h = (const float*)d_in[0];   // hidden_states [32768, 4096] f32
    const float* w = (const float*)d_in[1];   // wg_weight [16, 4096] f32
    float* out = (float*)d_out;               // [65536 idx-as-f32][65536 weights]

    const int blocks = T_TOKENS / (MT * WAVES);   // 512 blocks, 512 thr
    moe_gate_kernel<<<blocks, 512, 0, stream>>>(h, w, out);
}